// Round 17
// baseline (146.520 us; speedup 1.0000x reference)
//
#include <hip/hip_runtime.h>

#define C_DIM 1280
#define K_DIM 1280      // GEMM K = C
#define N_DIM 2560      // GEMM N = 2C
#define HWSZ 16
#define CHW (C_DIM*HWSZ)

#define GBM 256
#define GBN 320
#define GBK 64
#define GNT (K_DIM / GBK)   // 20 K-tiles

#define EPB 32              // edges per pose-MLP block
#define NBC 2048            // convert blocks (5 chunks each)

typedef __bf16 bf16;
typedef __attribute__((ext_vector_type(8))) __bf16 bf16x8;
typedef __attribute__((ext_vector_type(4))) __bf16 bf16x4;
typedef __attribute__((ext_vector_type(8))) unsigned short u16x8;
typedef __attribute__((ext_vector_type(4))) float f32x4;

template<int V> struct IC { static constexpr int v = V; };

__device__ __forceinline__ void gload_lds16(const void* g, void* l) {
  __builtin_amdgcn_global_load_lds(
      (const __attribute__((address_space(1))) void*)g,
      (__attribute__((address_space(3))) void*)l, 16, 0, 0);
}

#define SB __builtin_amdgcn_sched_barrier(0)

// ---------------- prep: CSR (block 0) + convert FIRST + pose MLP1 + W2 transpose -------
__global__ __launch_bounds__(256) void prep(
    const float* __restrict__ pose, const float* __restrict__ W1,
    const float* __restrict__ b1, bf16* __restrict__ h,
    const float* __restrict__ W2, bf16* __restrict__ W2t,
    const float* __restrict__ img32, bf16* __restrict__ imgb,
    const int* __restrict__ dst, const int* __restrict__ src,
    int* __restrict__ offsets, int2* __restrict__ pairs, int E, int N)
{
  const int b = blockIdx.x;
  const int t = threadIdx.x;
  const int NBP = (E / EPB) * 5;               // 1280 pose tasks

  if (b == 0) {
    // ---- CSR build, int4-vectorized, LDS bins ----
    __shared__ int cnt[1024];
    __shared__ int cur[1024];
    __shared__ int wsum[4];
    #pragma unroll
    for (int i = 0; i < 4; ++i) cnt[t + 256 * i] = 0;
    __syncthreads();
    const int4* dst4 = (const int4*)dst;
    const int4* src4 = (const int4*)src;
    const int E4 = E >> 2;
    for (int e4 = t; e4 < E4; e4 += 256) {
      const int4 d = dst4[e4];
      atomicAdd(&cnt[d.x], 1); atomicAdd(&cnt[d.y], 1);
      atomicAdd(&cnt[d.z], 1); atomicAdd(&cnt[d.w], 1);
    }
    __syncthreads();
    const int s0 = cnt[4*t], s1 = cnt[4*t+1], s2 = cnt[4*t+2], s3 = cnt[4*t+3];
    const int tot = s0 + s1 + s2 + s3;
    const int lane = t & 63, w = t >> 6;
    int x = tot;
    #pragma unroll
    for (int off = 1; off < 64; off <<= 1) {
      int y = __shfl_up(x, off);
      if (lane >= off) x += y;
    }
    if (lane == 63) wsum[w] = x;
    __syncthreads();
    int woff = 0;
    for (int i = 0; i < w; ++i) woff += wsum[i];
    const int excl = x + woff - tot;
    const int o0 = excl, o1 = o0 + s0, o2 = o1 + s1, o3 = o2 + s2;
    offsets[4*t] = o0; offsets[4*t+1] = o1; offsets[4*t+2] = o2; offsets[4*t+3] = o3;
    cur[4*t] = o0; cur[4*t+1] = o1; cur[4*t+2] = o2; cur[4*t+3] = o3;
    if (t == 0) offsets[N] = E;
    __syncthreads();
    for (int e4 = t; e4 < E4; e4 += 256) {
      const int4 d = dst4[e4];
      const int4 s = src4[e4];
      const int e = e4 * 4;
      int p;
      p = atomicAdd(&cur[d.x], 1); pairs[p] = make_int2(e,     s.x);
      p = atomicAdd(&cur[d.y], 1); pairs[p] = make_int2(e + 1, s.y);
      p = atomicAdd(&cur[d.z], 1); pairs[p] = make_int2(e + 2, s.z);
      p = atomicAdd(&cur[d.w], 1); pairs[p] = make_int2(e + 3, s.w);
    }
    return;
  }

  const int u = b - 1;

  if (u < NBC) {
    // ---- image fp32 -> bf16: 5 compile-time chunks, loads front-loaded ----
    const int cb = u;                       // 0..NBC-1
    f32x4 va[5], vb[5];
    #pragma unroll
    for (int j = 0; j < 5; ++j) {
      const size_t i = ((size_t)(cb + j * NBC) * 256 + t) * 8;
      va[j] = *(const f32x4*)(img32 + i);
      vb[j] = *(const f32x4*)(img32 + i + 4);
    }
    #pragma unroll
    for (int j = 0; j < 5; ++j) {
      const size_t i = ((size_t)(cb + j * NBC) * 256 + t) * 8;
      bf16x8 o;
      o[0]=(bf16)va[j][0]; o[1]=(bf16)va[j][1]; o[2]=(bf16)va[j][2]; o[3]=(bf16)va[j][3];
      o[4]=(bf16)vb[j][0]; o[5]=(bf16)vb[j][1]; o[6]=(bf16)vb[j][2]; o[7]=(bf16)vb[j][3];
      *(bf16x8*)(imgb + i) = o;
    }
    return;
  }

  if (u < NBC + NBP) {
    // ---- h = relu(pose @ W1 + b1): 32 edges x 256 channels per task ----
    const int l  = u - NBC;
    const int eg = l / 5;
    const int cc = l % 5;
    const int c  = cc * 256 + t;
    const int e0 = eg * EPB;
    float w[9];
    #pragma unroll
    for (int k = 0; k < 9; ++k) w[k] = W1[k * C_DIM + c];
    const float bias = b1[c];
    #pragma unroll 4
    for (int i = 0; i < EPB; ++i) {
      const float* p = pose + (size_t)(e0 + i) * 9;
      float s = bias;
      #pragma unroll
      for (int k = 0; k < 9; ++k) s += p[k] * w[k];
      s = s > 0.f ? s : 0.f;
      h[(size_t)(e0 + i) * C_DIM + c] = (bf16)s;
    }
    return;
  }

  // ---- W2 (1280 x 2560) -> W2t (2560 x 1280) bf16, vectorized ----
  const int tb = u - NBC - NBP;
  __shared__ float tile[32][33];
  const int n0 = (tb % (N_DIM / 32)) * 32;
  const int k0 = (tb / (N_DIM / 32)) * 32;
  const int r  = t >> 3;
  const int c4 = (t & 7) * 4;
  const f32x4 v = *(const f32x4*)(W2 + (size_t)(k0 + r) * N_DIM + n0 + c4);
  tile[r][c4] = v[0]; tile[r][c4+1] = v[1]; tile[r][c4+2] = v[2]; tile[r][c4+3] = v[3];
  __syncthreads();
  bf16x4 o;
  o[0] = (bf16)tile[c4+0][r];
  o[1] = (bf16)tile[c4+1][r];
  o[2] = (bf16)tile[c4+2][r];
  o[3] = (bf16)tile[c4+3][r];
  *(bf16x4*)(W2t + (size_t)(n0 + r) * K_DIM + k0 + c4) = o;
}

// ---------------- GEMM: 256x320 tile, 8 waves, 4-phase counted-vmcnt ----------------
// K-loop identical to r13; NEW epilogue: sigmoid -> per-wave LDS region -> coalesced
// bf16x8 stores (160B-contiguous runs instead of 32B scattered).
__global__ __launch_bounds__(512, 2) void gemm_sigmoid(
    const bf16* __restrict__ A, const bf16* __restrict__ Bt,
    const float* __restrict__ b2, bf16* __restrict__ Eo)
{
  __shared__ __align__(16) char Asm[2][GBM * GBK * 2];   // 2 x 32KB
  __shared__ __align__(16) char Bsm[2][GBN * GBK * 2];   // 2 x 40KB = 81920 B

  const int tid  = threadIdx.x;
  const int lane = tid & 63;
  const int wid  = tid >> 6;        // 8 waves: 2 (M) x 4 (N)
  const int wr   = wid >> 2;
  const int wc   = wid & 3;
  const int fr   = lane & 15;
  const int q    = lane >> 4;
  const int sw   = fr & 7;
  const int g0   = ((q ^ sw) << 4);
  const int g1   = (((4 + q) ^ sw) << 4);

  const int swzb = (blockIdx.x & 7) * 32 + (blockIdx.x >> 3);
  const int mb   = swzb >> 3;
  const int nb   = swzb & 7;
  const long bm  = (long)mb * GBM;
  const long bn  = (long)nb * GBN;

  const bf16* Agl = A  + bm * K_DIM;
  const bf16* Bgl = Bt + bn * K_DIM;

  f32x4 acc[8][5];
  #pragma unroll
  for (int m = 0; m < 8; m++)
    #pragma unroll
    for (int n = 0; n < 5; n++) acc[m][n] = f32x4{0.f, 0.f, 0.f, 0.f};

  auto STAGE_A = [&](int tt, int buf, int u) {
    const int G = u * 512 + tid;
    const int row = G >> 3, g = G & 7;
    const int kg = (g ^ (row & 7)) << 3;
    gload_lds16(Agl + (size_t)row * K_DIM + tt * GBK + kg, Asm[buf] + (size_t)G * 16);
  };
  auto STAGE_B = [&](int tt, int buf, int u) {
    const int G = u * 512 + tid;
    const int row = G >> 3, g = G & 7;
    const int kg = (g ^ (row & 7)) << 3;
    gload_lds16(Bgl + (size_t)row * K_DIM + tt * GBK + kg, Bsm[buf] + (size_t)G * 16);
  };

  // prologue: tile 0, issue order B0,B1,A0,B2,B3,A2,B4,A1,A3
  STAGE_B(0,0,0); STAGE_B(0,0,1); STAGE_A(0,0,0);
  STAGE_B(0,0,2); STAGE_B(0,0,3); STAGE_A(0,0,2); STAGE_B(0,0,4);
  STAGE_A(0,0,1); STAGE_A(0,0,3);
  asm volatile("s_waitcnt vmcnt(2)" ::: "memory");
  SB;
  __builtin_amdgcn_s_barrier();
  SB;

  auto tile_body = [&](auto PFc, int t) {
    constexpr bool PF = (bool)decltype(PFc)::v;
    const int cur = t & 1;
    const int nxt = cur ^ 1;
    const int tn  = t + 1;
    const char* Ab = Asm[cur];
    const char* Bb = Bsm[cur];

    bf16x8 bfr[5][2];

    auto do_phase = [&](auto Pc) {
      constexpr int p = decltype(Pc)::v;
      if constexpr (p == 0) {
        #pragma unroll
        for (int n = 0; n < 5; ++n) {
          const int rb = (wc * 80 + n * 16 + fr) << 7;
          bfr[n][0] = *(const bf16x8*)(Bb + rb + g0);
          bfr[n][1] = *(const bf16x8*)(Bb + rb + g1);
        }
      }
      bf16x8 a[2][2];
      #pragma unroll
      for (int mm = 0; mm < 2; ++mm) {
        const int ra = (wr * 128 + (2 * p + mm) * 16 + fr) << 7;
        a[mm][0] = *(const bf16x8*)(Ab + ra + g0);
        a[mm][1] = *(const bf16x8*)(Ab + ra + g1);
      }
      if constexpr (PF) {
        if constexpr (p == 0) { STAGE_B(tn,nxt,0); STAGE_B(tn,nxt,1); STAGE_A(tn,nxt,0); }
        if constexpr (p == 1) { STAGE_B(tn,nxt,2); STAGE_B(tn,nxt,3); STAGE_A(tn,nxt,2); STAGE_B(tn,nxt,4); }
        if constexpr (p == 2) { STAGE_A(tn,nxt,1); }
        if constexpr (p == 3) { STAGE_A(tn,nxt,3); }
      }
      SB;
      __builtin_amdgcn_s_barrier();
      asm volatile("s_waitcnt lgkmcnt(0)" ::: "memory");
      SB;
      __builtin_amdgcn_s_setprio(1);
      #pragma unroll
      for (int mm = 0; mm < 2; ++mm)
        #pragma unroll
        for (int n = 0; n < 5; ++n) {
          acc[2*p+mm][n] = __builtin_amdgcn_mfma_f32_16x16x32_bf16(a[mm][0], bfr[n][0], acc[2*p+mm][n], 0, 0, 0);
          acc[2*p+mm][n] = __builtin_amdgcn_mfma_f32_16x16x32_bf16(a[mm][1], bfr[n][1], acc[2*p+mm][n], 0, 0, 0);
        }
      __builtin_amdgcn_s_setprio(0);
      SB;
      if constexpr (p == 1) {
        if constexpr (PF) asm volatile("s_waitcnt vmcnt(7)" ::: "memory");
        else              asm volatile("s_waitcnt vmcnt(0)" ::: "memory");
        SB;
      }
      if constexpr (p == 3 && PF) {
        asm volatile("s_waitcnt vmcnt(2)" ::: "memory");
        SB;
      }
      __builtin_amdgcn_s_barrier();
      SB;
    };

    do_phase(IC<0>{});
    do_phase(IC<1>{});
    do_phase(IC<2>{});
    do_phase(IC<3>{});
  };

  for (int t = 0; t < GNT - 1; ++t) tile_body(IC<1>{}, t);
  tile_body(IC<0>{}, GNT - 1);

  // ---- epilogue: sigmoid -> per-wave LDS region -> coalesced bf16x8 stores ----
  // Bsm = 81920 B = 8 waves x 10240 B (64 rows x 80 cols bf16). Regions are
  // wave-private: no cross-wave barrier needed; intra-wave RAW ordered by lgkmcnt.
  char* reg = (char*)Bsm + wid * 10240;
  float bias[5];
  #pragma unroll
  for (int n = 0; n < 5; ++n) bias[n] = b2[bn + wc * 80 + n * 16 + fr];

  #pragma unroll
  for (int mh = 0; mh < 2; ++mh) {
    #pragma unroll
    for (int m2 = 0; m2 < 4; ++m2) {
      const int m = mh * 4 + m2;
      #pragma unroll
      for (int n = 0; n < 5; ++n)
        #pragma unroll
        for (int r = 0; r < 4; ++r) {
          const float v = acc[m][n][r] + bias[n];
          const float s = 1.f / (1.f + __expf(-v));
          *(bf16*)(reg + (((m2 * 16 + q * 4 + r) * 80 + n * 16 + fr) << 1)) = (bf16)s;
        }
    }
    asm volatile("s_waitcnt lgkmcnt(0)" ::: "memory");
    SB;
    #pragma unroll
    for (int it = 0; it < 10; ++it) {
      const int c  = it * 64 + lane;        // 640 chunks of 16B per half
      const int rl = c / 10;                // local row 0..63
      const int ci = c % 10;                // 16B chunk in row
      const bf16x8 v = *(const bf16x8*)(reg + ((rl * 80) << 1) + (ci << 4));
      const long rowg = bm + wr * 128 + mh * 64 + rl;
      *(bf16x8*)(Eo + rowg * N_DIM + bn + wc * 80 + ci * 8) = v;
    }
    asm volatile("s_waitcnt lgkmcnt(0)" ::: "memory");
    SB;
  }
}

// ---------------- scatter-mean: out[n] = mean_e(gamma*image_bf16[src]+beta) ----------------
__global__ __launch_bounds__(256) void scatter_mean(
    const ushort* __restrict__ Eo,      // E x 2560 bf16, (gamma,beta) interleaved
    const ushort* __restrict__ imgb16,  // N x C x 16 bf16 bits
    const int2* __restrict__ pairs,     // (eid, src) in CSR order
    const int* __restrict__ offsets,    // N+1
    float* __restrict__ out)            // N x C x 16 fp32
{
  const int n = blockIdx.x;
  const int c0 = blockIdx.y * 128;
  const int t = threadIdx.x;
  const int q = t & 1;
  const int cl = t >> 1;
  const int ca = c0 + cl;
  const int ioff = ca * HWSZ + q * 8;

  const int beg = offsets[n], end = offsets[n + 1];
  f32x4 aA0{0.f,0.f,0.f,0.f}, aA1{0.f,0.f,0.f,0.f};
  f32x4 aB0{0.f,0.f,0.f,0.f}, aB1{0.f,0.f,0.f,0.f};

  int2 p0{0,0}, p1{0,0};
  if (beg < end) p0 = pairs[beg];
  if (beg + 1 < end) p1 = pairs[beg + 1];

  auto edge = [&](int2 cp, f32x4& x0, f32x4& x1) {
    const u16x8 iv = *(const u16x8*)(imgb16 + (size_t)cp.y * CHW + ioff);
    const uint u = *(const uint*)(Eo + (size_t)cp.x * N_DIM + 2 * ca);
    const float g  = __uint_as_float(u << 16);
    const float be = __uint_as_float(u & 0xffff0000u);
    f32x4 i0, i1;
    i0[0] = __uint_as_float((uint)iv[0] << 16);
    i0[1] = __uint_as_float((uint)iv[1] << 16);
    i0[2] = __uint_as_float((uint)iv[2] << 16);
    i0[3] = __uint_as_float((uint)iv[3] << 16);
    i1[0] = __uint_as_float((uint)iv[4] << 16);
    i1[1] = __uint_as_float((uint)iv[5] << 16);
    i1[2] = __uint_as_float((uint)iv[6] << 16);
    i1[3] = __uint_as_float((uint)iv[7] << 16);
    x0 += g * i0 + be;
    x1 += g * i1 + be;
  };

  int ei = beg;
  for (; ei + 1 < end; ei += 2) {
    const int2 c0p = p0, c1p = p1;
    if (ei + 2 < end) p0 = pairs[ei + 2];
    if (ei + 3 < end) p1 = pairs[ei + 3];
    edge(c0p, aA0, aA1);
    edge(c1p, aB0, aB1);
  }
  if (ei < end) edge(p0, aA0, aA1);

  const int cnt = end - beg;
  const float inv = cnt > 0 ? 1.f / (float)cnt : 0.f;
  const f32x4 r0 = (aA0 + aB0) * inv;
  const f32x4 r1 = (aA1 + aB1) * inv;
  float* ob = out + (size_t)n * CHW + ioff;
  __builtin_nontemporal_store(r0, (f32x4*)ob);
  __builtin_nontemporal_store(r1, (f32x4*)(ob + 4));
}

// ---------------- launch ----------------
extern "C" void kernel_launch(void* const* d_in, const int* in_sizes, int n_in,
                              void* d_out, int out_size, void* d_ws, size_t ws_size,
                              hipStream_t stream) {
  const float* pose  = (const float*)d_in[0];
  const float* image = (const float*)d_in[1];
  const float* W1    = (const float*)d_in[2];
  const float* b1    = (const float*)d_in[3];
  const float* W2    = (const float*)d_in[4];
  const float* b2    = (const float*)d_in[5];
  const int*   src   = (const int*)d_in[6];
  const int*   dst   = (const int*)d_in[7];
  const int E = in_sizes[6];                     // 8192
  const int N = in_sizes[1] / CHW;               // 1024
  float* out = (float*)d_out;

  char* ws = (char*)d_ws;
  size_t off = 0;
  auto alloc = [&](size_t bytes) {
    void* p = ws + off;
    off = (off + bytes + 255) & ~(size_t)255;
    return p;
  };
  bf16* h     = (bf16*)alloc((size_t)E * C_DIM * sizeof(bf16));
  bf16* W2t   = (bf16*)alloc((size_t)N_DIM * K_DIM * sizeof(bf16));
  bf16* Eout  = (bf16*)alloc((size_t)E * N_DIM * sizeof(bf16));
  bf16* imgb  = (bf16*)alloc((size_t)N * CHW * sizeof(bf16));
  int* offs   = (int*)alloc((size_t)(N + 1) * sizeof(int));
  int2* pairs = (int2*)alloc((size_t)E * sizeof(int2));

  // prep: CSR (block 0) + convert-first + pose MLP1 + W2 transpose
  const int nb_prep = 1 + NBC + (E / EPB) * 5 + (N_DIM / 32) * (K_DIM / 32);
  prep<<<nb_prep, 256, 0, stream>>>(pose, W1, b1, h, W2, W2t, image, imgb,
                                    dst, src, offs, pairs, E, N);

  // GEMM (256x320, 4-phase counted-vmcnt, 256 blocks = 1/CU)
  gemm_sigmoid<<<(E / GBM) * (N_DIM / GBN), 512, 0, stream>>>(h, W2t, b2, Eout);

  // FiLM + segment mean (bf16 image)
  scatter_mean<<<dim3(N, 10), 256, 0, stream>>>(
      (const ushort*)Eout, (const ushort*)imgb, pairs, offs, out);
}

// Round 18
// 139.694 us; speedup vs baseline: 1.0489x; 1.0489x over previous
//
#include <hip/hip_runtime.h>

#define C_DIM 1280
#define K_DIM 1280      // GEMM K = C
#define N_DIM 2560      // GEMM N = 2C
#define HWSZ 16
#define CHW (C_DIM*HWSZ)

#define GBM 256
#define GBN 320
#define GBK 64
#define GNT (K_DIM / GBK)   // 20 K-tiles

#define EPB 32              // edges per pose-MLP block
#define NBC 2048            // convert blocks (5 chunks each)

typedef __bf16 bf16;
typedef __attribute__((ext_vector_type(8))) __bf16 bf16x8;
typedef __attribute__((ext_vector_type(4))) __bf16 bf16x4;
typedef __attribute__((ext_vector_type(8))) unsigned short u16x8;
typedef __attribute__((ext_vector_type(4))) float f32x4;

template<int V> struct IC { static constexpr int v = V; };

__device__ __forceinline__ void gload_lds16(const void* g, void* l) {
  __builtin_amdgcn_global_load_lds(
      (const __attribute__((address_space(1))) void*)g,
      (__attribute__((address_space(3))) void*)l, 16, 0, 0);
}

#define SB __builtin_amdgcn_sched_barrier(0)

// ---------------- prep: CSR (block 0) + pose MLP1 + W2 transpose + convert (r13) -------
__global__ __launch_bounds__(256) void prep(
    const float* __restrict__ pose, const float* __restrict__ W1,
    const float* __restrict__ b1, bf16* __restrict__ h,
    const float* __restrict__ W2, bf16* __restrict__ W2t,
    const float* __restrict__ img32, bf16* __restrict__ imgb,
    const int* __restrict__ dst, const int* __restrict__ src,
    int* __restrict__ offsets, int2* __restrict__ pairs, int E, int N)
{
  const int b = blockIdx.x;
  const int t = threadIdx.x;
  const int NBP = (E / EPB) * 5;               // 1280 pose tasks
  const int NBT = (N_DIM / 32) * (K_DIM / 32); // 3200 transpose tasks

  if (b == 0) {
    // ---- CSR build, int4-vectorized, LDS bins ----
    __shared__ int cnt[1024];
    __shared__ int cur[1024];
    __shared__ int wsum[4];
    #pragma unroll
    for (int i = 0; i < 4; ++i) cnt[t + 256 * i] = 0;
    __syncthreads();
    const int4* dst4 = (const int4*)dst;
    const int4* src4 = (const int4*)src;
    const int E4 = E >> 2;
    for (int e4 = t; e4 < E4; e4 += 256) {
      const int4 d = dst4[e4];
      atomicAdd(&cnt[d.x], 1); atomicAdd(&cnt[d.y], 1);
      atomicAdd(&cnt[d.z], 1); atomicAdd(&cnt[d.w], 1);
    }
    __syncthreads();
    const int s0 = cnt[4*t], s1 = cnt[4*t+1], s2 = cnt[4*t+2], s3 = cnt[4*t+3];
    const int tot = s0 + s1 + s2 + s3;
    const int lane = t & 63, w = t >> 6;
    int x = tot;
    #pragma unroll
    for (int off = 1; off < 64; off <<= 1) {
      int y = __shfl_up(x, off);
      if (lane >= off) x += y;
    }
    if (lane == 63) wsum[w] = x;
    __syncthreads();
    int woff = 0;
    for (int i = 0; i < w; ++i) woff += wsum[i];
    const int excl = x + woff - tot;
    const int o0 = excl, o1 = o0 + s0, o2 = o1 + s1, o3 = o2 + s2;
    offsets[4*t] = o0; offsets[4*t+1] = o1; offsets[4*t+2] = o2; offsets[4*t+3] = o3;
    cur[4*t] = o0; cur[4*t+1] = o1; cur[4*t+2] = o2; cur[4*t+3] = o3;
    if (t == 0) offsets[N] = E;
    __syncthreads();
    for (int e4 = t; e4 < E4; e4 += 256) {
      const int4 d = dst4[e4];
      const int4 s = src4[e4];
      const int e = e4 * 4;
      int p;
      p = atomicAdd(&cur[d.x], 1); pairs[p] = make_int2(e,     s.x);
      p = atomicAdd(&cur[d.y], 1); pairs[p] = make_int2(e + 1, s.y);
      p = atomicAdd(&cur[d.z], 1); pairs[p] = make_int2(e + 2, s.z);
      p = atomicAdd(&cur[d.w], 1); pairs[p] = make_int2(e + 3, s.w);
    }
    return;
  }

  const int pb = b - 1;
  if (pb < NBP) {
    // ---- h = relu(pose @ W1 + b1): 32 edges x 256 channels per block ----
    const int eg = pb / 5;
    const int cc = pb % 5;
    const int c  = cc * 256 + t;
    const int e0 = eg * EPB;
    float w[9];
    #pragma unroll
    for (int k = 0; k < 9; ++k) w[k] = W1[k * C_DIM + c];
    const float bias = b1[c];
    #pragma unroll 4
    for (int i = 0; i < EPB; ++i) {
      const float* p = pose + (size_t)(e0 + i) * 9;
      float s = bias;
      #pragma unroll
      for (int k = 0; k < 9; ++k) s += p[k] * w[k];
      s = s > 0.f ? s : 0.f;
      h[(size_t)(e0 + i) * C_DIM + c] = (bf16)s;
    }
    return;
  }

  if (pb < NBP + NBT) {
    // ---- W2 (1280 x 2560) -> W2t (2560 x 1280) bf16, vectorized ----
    const int tb = pb - NBP;
    __shared__ float tile[32][33];
    const int n0 = (tb % (N_DIM / 32)) * 32;
    const int k0 = (tb / (N_DIM / 32)) * 32;
    const int r  = t >> 3;
    const int c4 = (t & 7) * 4;
    const f32x4 v = *(const f32x4*)(W2 + (size_t)(k0 + r) * N_DIM + n0 + c4);
    tile[r][c4] = v[0]; tile[r][c4+1] = v[1]; tile[r][c4+2] = v[2]; tile[r][c4+3] = v[3];
    __syncthreads();
    bf16x4 o;
    o[0] = (bf16)tile[c4+0][r];
    o[1] = (bf16)tile[c4+1][r];
    o[2] = (bf16)tile[c4+2][r];
    o[3] = (bf16)tile[c4+3][r];
    *(bf16x4*)(W2t + (size_t)(n0 + r) * K_DIM + k0 + c4) = o;
    return;
  }

  // ---- image fp32 -> bf16: 5 compile-time chunks, loads front-loaded ----
  const int cb = pb - NBP - NBT;          // 0..NBC-1
  f32x4 va[5], vb[5];
  #pragma unroll
  for (int j = 0; j < 5; ++j) {
    const size_t i = ((size_t)(cb + j * NBC) * 256 + t) * 8;
    va[j] = *(const f32x4*)(img32 + i);
    vb[j] = *(const f32x4*)(img32 + i + 4);
  }
  #pragma unroll
  for (int j = 0; j < 5; ++j) {
    const size_t i = ((size_t)(cb + j * NBC) * 256 + t) * 8;
    bf16x8 o;
    o[0]=(bf16)va[j][0]; o[1]=(bf16)va[j][1]; o[2]=(bf16)va[j][2]; o[3]=(bf16)va[j][3];
    o[4]=(bf16)vb[j][0]; o[5]=(bf16)vb[j][1]; o[6]=(bf16)vb[j][2]; o[7]=(bf16)vb[j][3];
    *(bf16x8*)(imgb + i) = o;
  }
}

// ---------------- GEMM: 256x320 tile, 8 waves, 4-phase counted-vmcnt (r13 exact) -------
__global__ __launch_bounds__(512, 2) void gemm_sigmoid(
    const bf16* __restrict__ A, const bf16* __restrict__ Bt,
    const float* __restrict__ b2, bf16* __restrict__ Eo)
{
  __shared__ __align__(16) char Asm[2][GBM * GBK * 2];   // 2 x 32KB
  __shared__ __align__(16) char Bsm[2][GBN * GBK * 2];   // 2 x 40KB

  const int tid  = threadIdx.x;
  const int lane = tid & 63;
  const int wid  = tid >> 6;        // 8 waves: 2 (M) x 4 (N)
  const int wr   = wid >> 2;
  const int wc   = wid & 3;
  const int fr   = lane & 15;
  const int q    = lane >> 4;
  const int sw   = fr & 7;
  const int g0   = ((q ^ sw) << 4);
  const int g1   = (((4 + q) ^ sw) << 4);

  const int swzb = (blockIdx.x & 7) * 32 + (blockIdx.x >> 3);
  const int mb   = swzb >> 3;
  const int nb   = swzb & 7;
  const long bm  = (long)mb * GBM;
  const long bn  = (long)nb * GBN;

  const bf16* Agl = A  + bm * K_DIM;
  const bf16* Bgl = Bt + bn * K_DIM;

  f32x4 acc[8][5];
  #pragma unroll
  for (int m = 0; m < 8; m++)
    #pragma unroll
    for (int n = 0; n < 5; n++) acc[m][n] = f32x4{0.f, 0.f, 0.f, 0.f};

  auto STAGE_A = [&](int tt, int buf, int u) {
    const int G = u * 512 + tid;
    const int row = G >> 3, g = G & 7;
    const int kg = (g ^ (row & 7)) << 3;
    gload_lds16(Agl + (size_t)row * K_DIM + tt * GBK + kg, Asm[buf] + (size_t)G * 16);
  };
  auto STAGE_B = [&](int tt, int buf, int u) {
    const int G = u * 512 + tid;
    const int row = G >> 3, g = G & 7;
    const int kg = (g ^ (row & 7)) << 3;
    gload_lds16(Bgl + (size_t)row * K_DIM + tt * GBK + kg, Bsm[buf] + (size_t)G * 16);
  };

  // prologue: tile 0, issue order B0,B1,A0,B2,B3,A2,B4,A1,A3
  STAGE_B(0,0,0); STAGE_B(0,0,1); STAGE_A(0,0,0);
  STAGE_B(0,0,2); STAGE_B(0,0,3); STAGE_A(0,0,2); STAGE_B(0,0,4);
  STAGE_A(0,0,1); STAGE_A(0,0,3);
  asm volatile("s_waitcnt vmcnt(2)" ::: "memory");
  SB;
  __builtin_amdgcn_s_barrier();
  SB;

  auto tile_body = [&](auto PFc, int t) {
    constexpr bool PF = (bool)decltype(PFc)::v;
    const int cur = t & 1;
    const int nxt = cur ^ 1;
    const int tn  = t + 1;
    const char* Ab = Asm[cur];
    const char* Bb = Bsm[cur];

    bf16x8 bfr[5][2];

    auto do_phase = [&](auto Pc) {
      constexpr int p = decltype(Pc)::v;
      if constexpr (p == 0) {
        #pragma unroll
        for (int n = 0; n < 5; ++n) {
          const int rb = (wc * 80 + n * 16 + fr) << 7;
          bfr[n][0] = *(const bf16x8*)(Bb + rb + g0);
          bfr[n][1] = *(const bf16x8*)(Bb + rb + g1);
        }
      }
      bf16x8 a[2][2];
      #pragma unroll
      for (int mm = 0; mm < 2; ++mm) {
        const int ra = (wr * 128 + (2 * p + mm) * 16 + fr) << 7;
        a[mm][0] = *(const bf16x8*)(Ab + ra + g0);
        a[mm][1] = *(const bf16x8*)(Ab + ra + g1);
      }
      if constexpr (PF) {
        if constexpr (p == 0) { STAGE_B(tn,nxt,0); STAGE_B(tn,nxt,1); STAGE_A(tn,nxt,0); }
        if constexpr (p == 1) { STAGE_B(tn,nxt,2); STAGE_B(tn,nxt,3); STAGE_A(tn,nxt,2); STAGE_B(tn,nxt,4); }
        if constexpr (p == 2) { STAGE_A(tn,nxt,1); }
        if constexpr (p == 3) { STAGE_A(tn,nxt,3); }
      }
      SB;
      __builtin_amdgcn_s_barrier();
      asm volatile("s_waitcnt lgkmcnt(0)" ::: "memory");
      SB;
      __builtin_amdgcn_s_setprio(1);
      #pragma unroll
      for (int mm = 0; mm < 2; ++mm)
        #pragma unroll
        for (int n = 0; n < 5; ++n) {
          acc[2*p+mm][n] = __builtin_amdgcn_mfma_f32_16x16x32_bf16(a[mm][0], bfr[n][0], acc[2*p+mm][n], 0, 0, 0);
          acc[2*p+mm][n] = __builtin_amdgcn_mfma_f32_16x16x32_bf16(a[mm][1], bfr[n][1], acc[2*p+mm][n], 0, 0, 0);
        }
      __builtin_amdgcn_s_setprio(0);
      SB;
      if constexpr (p == 1) {
        if constexpr (PF) asm volatile("s_waitcnt vmcnt(7)" ::: "memory");
        else              asm volatile("s_waitcnt vmcnt(0)" ::: "memory");
        SB;
      }
      if constexpr (p == 3 && PF) {
        asm volatile("s_waitcnt vmcnt(2)" ::: "memory");
        SB;
      }
      __builtin_amdgcn_s_barrier();
      SB;
    };

    do_phase(IC<0>{});
    do_phase(IC<1>{});
    do_phase(IC<2>{});
    do_phase(IC<3>{});
  };

  for (int t = 0; t < GNT - 1; ++t) tile_body(IC<1>{}, t);
  tile_body(IC<0>{}, GNT - 1);

  // epilogue: sigmoid(acc + b2) -> bf16 (r13 scattered-store version)
  #pragma unroll
  for (int m = 0; m < 8; ++m) {
    const long rowb = bm + wr * 128 + m * 16 + q * 4;
    #pragma unroll
    for (int n = 0; n < 5; ++n) {
      const long col = bn + wc * 80 + n * 16 + fr;
      const float bias = b2[col];
      #pragma unroll
      for (int r = 0; r < 4; ++r) {
        float v = acc[m][n][r] + bias;
        Eo[(rowb + r) * N_DIM + col] = (bf16)(1.f / (1.f + __expf(-v)));
      }
    }
  }
}

// ---------------- scatter-mean: 4-edge software pipeline ----------------
// grid (N, 10); block 256. 128 ch/block; q=t&1 hw-octet, cl=t>>1 channel.
__global__ __launch_bounds__(256) void scatter_mean(
    const ushort* __restrict__ Eo,      // E x 2560 bf16, (gamma,beta) interleaved
    const ushort* __restrict__ imgb16,  // N x C x 16 bf16 bits
    const int2* __restrict__ pairs,     // (eid, src) in CSR order
    const int* __restrict__ offsets,    // N+1
    float* __restrict__ out)            // N x C x 16 fp32
{
  const int n = blockIdx.x;
  const int c0 = blockIdx.y * 128;
  const int t = threadIdx.x;
  const int q = t & 1;
  const int cl = t >> 1;
  const int ca = c0 + cl;
  const int ioff = ca * HWSZ + q * 8;

  const int beg = offsets[n], end = offsets[n + 1];
  f32x4 accA0{0.f,0.f,0.f,0.f}, accA1{0.f,0.f,0.f,0.f};
  f32x4 accB0{0.f,0.f,0.f,0.f}, accB1{0.f,0.f,0.f,0.f};

  auto accum = [&](u16x8 iv, uint u, f32x4& x0, f32x4& x1) {
    const float g  = __uint_as_float(u << 16);
    const float be = __uint_as_float(u & 0xffff0000u);
    f32x4 i0, i1;
    i0[0] = __uint_as_float((uint)iv[0] << 16);
    i0[1] = __uint_as_float((uint)iv[1] << 16);
    i0[2] = __uint_as_float((uint)iv[2] << 16);
    i0[3] = __uint_as_float((uint)iv[3] << 16);
    i1[0] = __uint_as_float((uint)iv[4] << 16);
    i1[1] = __uint_as_float((uint)iv[5] << 16);
    i1[2] = __uint_as_float((uint)iv[6] << 16);
    i1[3] = __uint_as_float((uint)iv[7] << 16);
    x0 += g * i0 + be;
    x1 += g * i1 + be;
  };

  int2 pr[4];
  #pragma unroll
  for (int j = 0; j < 4; ++j)
    pr[j] = (beg + j < end) ? pairs[beg + j] : make_int2(0, 0);

  int ei = beg;
  for (; ei + 3 < end; ei += 4) {
    // issue all 8 loads before any accumulate (4 img + 4 gb in flight)
    u16x8 iv[4]; uint gu[4];
    #pragma unroll
    for (int j = 0; j < 4; ++j) {
      iv[j] = *(const u16x8*)(imgb16 + (size_t)pr[j].y * CHW + ioff);
      gu[j] = *(const uint*)(Eo + (size_t)pr[j].x * N_DIM + 2 * ca);
    }
    // refill prefetch for next iteration
    int2 nx[4];
    #pragma unroll
    for (int j = 0; j < 4; ++j)
      nx[j] = (ei + 4 + j < end) ? pairs[ei + 4 + j] : make_int2(0, 0);
    accum(iv[0], gu[0], accA0, accA1);
    accum(iv[1], gu[1], accB0, accB1);
    accum(iv[2], gu[2], accA0, accA1);
    accum(iv[3], gu[3], accB0, accB1);
    #pragma unroll
    for (int j = 0; j < 4; ++j) pr[j] = nx[j];
  }
  for (; ei < end; ++ei) {
    const int2 cp = pairs[ei];
    const u16x8 iv = *(const u16x8*)(imgb16 + (size_t)cp.y * CHW + ioff);
    const uint gu = *(const uint*)(Eo + (size_t)cp.x * N_DIM + 2 * ca);
    accum(iv, gu, accA0, accA1);
  }

  const int cnt = end - beg;
  const float inv = cnt > 0 ? 1.f / (float)cnt : 0.f;
  const f32x4 r0 = (accA0 + accB0) * inv;
  const f32x4 r1 = (accA1 + accB1) * inv;
  float* ob = out + (size_t)n * CHW + ioff;
  __builtin_nontemporal_store(r0, (f32x4*)ob);
  __builtin_nontemporal_store(r1, (f32x4*)(ob + 4));
}

// ---------------- launch ----------------
extern "C" void kernel_launch(void* const* d_in, const int* in_sizes, int n_in,
                              void* d_out, int out_size, void* d_ws, size_t ws_size,
                              hipStream_t stream) {
  const float* pose  = (const float*)d_in[0];
  const float* image = (const float*)d_in[1];
  const float* W1    = (const float*)d_in[2];
  const float* b1    = (const float*)d_in[3];
  const float* W2    = (const float*)d_in[4];
  const float* b2    = (const float*)d_in[5];
  const int*   src   = (const int*)d_in[6];
  const int*   dst   = (const int*)d_in[7];
  const int E = in_sizes[6];                     // 8192
  const int N = in_sizes[1] / CHW;               // 1024
  float* out = (float*)d_out;

  char* ws = (char*)d_ws;
  size_t off = 0;
  auto alloc = [&](size_t bytes) {
    void* p = ws + off;
    off = (off + bytes + 255) & ~(size_t)255;
    return p;
  };
  bf16* h     = (bf16*)alloc((size_t)E * C_DIM * sizeof(bf16));
  bf16* W2t   = (bf16*)alloc((size_t)N_DIM * K_DIM * sizeof(bf16));
  bf16* Eout  = (bf16*)alloc((size_t)E * N_DIM * sizeof(bf16));
  bf16* imgb  = (bf16*)alloc((size_t)N * CHW * sizeof(bf16));
  int* offs   = (int*)alloc((size_t)(N + 1) * sizeof(int));
  int2* pairs = (int2*)alloc((size_t)E * sizeof(int2));

  // prep: CSR + pose MLP1 + W2 transpose + convert (r13 ordering)
  const int nb_prep = 1 + (E / EPB) * 5 + (N_DIM / 32) * (K_DIM / 32) + NBC;
  prep<<<nb_prep, 256, 0, stream>>>(pose, W1, b1, h, W2, W2t, image, imgb,
                                    dst, src, offs, pairs, E, N);

  // GEMM (256x320, 4-phase counted-vmcnt, 256 blocks = 1/CU)
  gemm_sigmoid<<<(E / GBM) * (N_DIM / GBN), 512, 0, stream>>>(h, W2t, b2, Eout);

  // FiLM + segment mean (bf16 image, 4-edge pipelined)
  scatter_mean<<<dim3(N, 10), 256, 0, stream>>>(
      (const ushort*)Eout, (const ushort*)imgb, pairs, offs, out);
}